// Round 12
// baseline (528.051 us; speedup 1.0000x reference)
//
#include <hip/hip_runtime.h>

#define SEQ 2048
#define BATCH 4
#define DIM 1024
#define NHEAD 16
#define DHEAD 64

typedef __bf16 bf16;
typedef __bf16 bf16x8 __attribute__((ext_vector_type(8)));
typedef short bf16x4s __attribute__((ext_vector_type(4)));
typedef float f32x4 __attribute__((ext_vector_type(4)));
typedef unsigned int u32x4 __attribute__((ext_vector_type(4)));
typedef unsigned short u16;
typedef unsigned int u32;

__device__ __forceinline__ void gld16(const void* g, void* l) {
  __builtin_amdgcn_global_load_lds((__attribute__((address_space(1))) void*)(void*)g,
                                   (__attribute__((address_space(3))) void*)l, 16, 0, 0);
}

__device__ __forceinline__ u16 f2b(float f) {  // fp32 -> bf16 bits, RNE
  u32 u = __builtin_bit_cast(u32, f);
  u32 r = (u + 0x7FFFu + ((u >> 16) & 1u)) >> 16;
  return (u16)r;
}

// pack two f32 -> (bf16(f1)<<16)|bf16(f0), round-half-up (==RNE except exact ties)
__device__ __forceinline__ u32 pk2(float f0, float f1) {
  const u32 a = __builtin_bit_cast(u32, f1) + 0x8000u;
  const u32 b = __builtin_bit_cast(u32, f0) + 0x8000u;
  return __builtin_amdgcn_perm(a, b, 0x07060302u);
}

// K=16 bf16 MFMA: A/B = 4 bf16 (2 VGPR), layout A[m=lane&15][k=quad*4+j]
__device__ __forceinline__ f32x4 mfma16(bf16x4s a, bf16x4s b, f32x4 c) {
#if __has_builtin(__builtin_amdgcn_mfma_f32_16x16x16bf16_1k)
  return __builtin_amdgcn_mfma_f32_16x16x16bf16_1k(a, b, c, 0, 0, 0);
#else
  asm volatile("v_mfma_f32_16x16x16_bf16 %0, %1, %2, %0"
               : "+v"(c) : "v"(a), "v"(b));
  return c;
#endif
}

__device__ __forceinline__ void cvt16_store(const float4 v[4], u16* dst) {
  union { u16 h[16]; uint4 q[2]; } pk;
#pragma unroll
  for (int j = 0; j < 4; ++j) {
    pk.h[j * 4 + 0] = f2b(v[j].x);
    pk.h[j * 4 + 1] = f2b(v[j].y);
    pk.h[j * 4 + 2] = f2b(v[j].z);
    pk.h[j * 4 + 3] = f2b(v[j].w);
  }
  ((uint4*)dst)[0] = pk.q[0];
  ((uint4*)dst)[1] = pk.q[1];
}

// ---------------- K0: one-shot f32 -> bf16 conversion ----------------
__global__ __launch_bounds__(256) void k_cvt(
    const float* __restrict__ inp, const float* __restrict__ wqkv,
    const float* __restrict__ wproj, u16* __restrict__ xb,
    u16* __restrict__ wqkvb, u16* __restrict__ wprojb) {
  const int idx = blockIdx.x * 256 + threadIdx.x;
  const float4* src;
  u16* dst;
  int off;
  if (idx < 2097152)      { src = (const float4*)inp;   dst = xb;     off = idx; }
  else if (idx < 2883584) { src = (const float4*)wqkv;  dst = wqkvb;  off = idx - 2097152; }
  else                    { src = (const float4*)wproj; dst = wprojb; off = idx - 2883584; }
  const float4 v = src[off];
  union { u16 h[4]; uint2 q; } pk;
  pk.h[0] = f2b(v.x); pk.h[1] = f2b(v.y); pk.h[2] = f2b(v.z); pk.h[3] = f2b(v.w);
  *(uint2*)(dst + (size_t)off * 4) = pk.q;
}

// ---------------- K1a: QKV projection, all-bf16, async staging ----------------
__global__ __launch_bounds__(256, 2) void k_qkv_a(
    const u16* __restrict__ xb, const u16* __restrict__ wb,
    const float* __restrict__ bqkv, u16* __restrict__ q,
    u16* __restrict__ kk, u16* __restrict__ v) {
  __shared__ __align__(16) u16 Asm[128 * 32];
  __shared__ __align__(16) u16 Bsm[128 * 32];
  const int bn = blockIdx.x;   // 0..23
  const int bm = blockIdx.y;   // 0..63
  const int tid = threadIdx.x;
  const int wave = tid >> 6, lane = tid & 63;
  const int col = lane & 15, quad = lane >> 4;
  const int b = bm >> 4;
  const int s0 = (bm & 15) * 128;
  const int c0 = wave * 2;
  const int srow0 = c0 * 16 + (lane >> 2);
  const int kc = (lane & 3) * 8;
  const u16* gA0 = xb + (size_t)((s0 + srow0) * 4 + b) * 1024 + kc;
  const u16* gA1 = xb + (size_t)((s0 + srow0 + 16) * 4 + b) * 1024 + kc;
  const u16* gB0 = wb + (size_t)(bn * 128 + srow0) * 1024 + kc;
  const u16* gB1 = wb + (size_t)(bn * 128 + srow0 + 16) * 1024 + kc;
  u16* lA0 = Asm + c0 * 512;
  u16* lA1 = Asm + c0 * 512 + 512;
  u16* lB0 = Bsm + c0 * 512;
  u16* lB1 = Bsm + c0 * 512 + 512;
  const int wm = (wave >> 1) * 64, wn = (wave & 1) * 64;

  f32x4 acc[4][4];
#pragma unroll
  for (int i = 0; i < 4; ++i)
#pragma unroll
    for (int j = 0; j < 4; ++j) acc[i][j] = f32x4{0.f, 0.f, 0.f, 0.f};

  for (int k0 = 0; k0 < 1024; k0 += 32) {
    __syncthreads();
    gld16(gA0 + k0, lA0);
    gld16(gA1 + k0, lA1);
    gld16(gB0 + k0, lB0);
    gld16(gB1 + k0, lB1);
    __builtin_amdgcn_s_waitcnt(0);
    __syncthreads();
    bf16x8 af[4], bfr[4];
#pragma unroll
    for (int i = 0; i < 4; ++i)
      af[i] = *(const bf16x8*)(Asm + (wm + i * 16 + col) * 32 + quad * 8);
#pragma unroll
    for (int j = 0; j < 4; ++j)
      bfr[j] = *(const bf16x8*)(Bsm + (wn + j * 16 + col) * 32 + quad * 8);
#pragma unroll
    for (int i = 0; i < 4; ++i)
#pragma unroll
      for (int j = 0; j < 4; ++j)
        acc[i][j] = __builtin_amdgcn_mfma_f32_16x16x32_bf16(af[i], bfr[j], acc[i][j], 0, 0, 0);
  }

  const float QS = 0.125f * 1.44269504088896f;  // SCALE * log2(e)
#pragma unroll
  for (int j = 0; j < 4; ++j) {
    const int n = bn * 128 + wn + j * 16 + col;
    const float bias = bqkv[n];
    const int region = n >> 10;  // 0=q 1=k 2=v
    const int hh = (n >> 6) & 15;
    const int dh = n & 63;
    if (region == 2) {  // V transposed: [B,H,DH,S]
      const size_t baseT = ((size_t)(b * 16 + hh) * 64 + dh) * 2048;
#pragma unroll
      for (int i = 0; i < 4; ++i) {
        const int srow = s0 + wm + i * 16 + quad * 4;
#pragma unroll
        for (int r = 0; r < 4; ++r)
          v[baseT + srow + r] = f2b(acc[i][j][r] + bias);
      }
    } else {
      u16* outp = (region == 0) ? q : kk;
      const float mult = (region == 0) ? QS : 1.0f;
      const size_t base = ((size_t)(b * 16 + hh) * 2048) * 64 + dh;
#pragma unroll
      for (int i = 0; i < 4; ++i) {
        const int srow = s0 + wm + i * 16 + quad * 4;
#pragma unroll
        for (int r = 0; r < 4; ++r)
          outp[base + (size_t)(srow + r) * 64] = f2b((acc[i][j][r] + bias) * mult);
      }
    }
  }
}

// ---------------- K1b: QKV projection, f32-inline-convert (fallback) ----------------
__global__ __launch_bounds__(256, 2) void k_qkv_f32(
    const float* __restrict__ inp, const float* __restrict__ Wqkv,
    const float* __restrict__ bqkv, u16* __restrict__ q,
    u16* __restrict__ kk, u16* __restrict__ v, int b_fixed) {
  __shared__ __align__(16) u16 Asm[128 * 32];
  __shared__ __align__(16) u16 Bsm[128 * 32];
  const int bn = blockIdx.x;
  const int bm = blockIdx.y;
  const int tid = threadIdx.x;
  const int wave = tid >> 6, lane = tid & 63;
  const int col = lane & 15, quad = lane >> 4;
  int b, s0, hb;
  if (b_fixed < 0) { b = bm >> 4; s0 = (bm & 15) * 128; hb = b * 16; }
  else             { b = b_fixed; s0 = bm * 128;        hb = 0; }

  const int arow = tid >> 1;
  const int kseg = (tid & 1) * 16;
  const float* gA = inp + (size_t)((s0 + arow) * 4 + b) * 1024 + kseg;
  const float* gB = Wqkv + (size_t)(bn * 128 + arow) * 1024 + kseg;
  u16* lA = Asm + arow * 32 + kseg;
  u16* lB = Bsm + arow * 32 + kseg;
  const int wm = (wave >> 1) * 64, wn = (wave & 1) * 64;

  f32x4 acc[4][4];
#pragma unroll
  for (int i = 0; i < 4; ++i)
#pragma unroll
    for (int j = 0; j < 4; ++j) acc[i][j] = f32x4{0.f, 0.f, 0.f, 0.f};

  for (int k0 = 0; k0 < 1024; k0 += 32) {
    float4 av[4], bv[4];
#pragma unroll
    for (int u = 0; u < 4; ++u) av[u] = *(const float4*)(gA + k0 + u * 4);
#pragma unroll
    for (int u = 0; u < 4; ++u) bv[u] = *(const float4*)(gB + k0 + u * 4);
    __syncthreads();
    cvt16_store(av, lA);
    cvt16_store(bv, lB);
    __syncthreads();
    bf16x8 af[4], bfr[4];
#pragma unroll
    for (int i = 0; i < 4; ++i)
      af[i] = *(const bf16x8*)(Asm + (wm + i * 16 + col) * 32 + quad * 8);
#pragma unroll
    for (int j = 0; j < 4; ++j)
      bfr[j] = *(const bf16x8*)(Bsm + (wn + j * 16 + col) * 32 + quad * 8);
#pragma unroll
    for (int i = 0; i < 4; ++i)
#pragma unroll
      for (int j = 0; j < 4; ++j)
        acc[i][j] = __builtin_amdgcn_mfma_f32_16x16x32_bf16(af[i], bfr[j], acc[i][j], 0, 0, 0);
  }

  const float QS = 0.125f * 1.44269504088896f;
#pragma unroll
  for (int j = 0; j < 4; ++j) {
    const int n = bn * 128 + wn + j * 16 + col;
    const float bias = bqkv[n];
    const int region = n >> 10;
    const int hh = (n >> 6) & 15;
    const int dh = n & 63;
    if (region == 2) {
      const size_t baseT = ((size_t)(hb + hh) * 64 + dh) * 2048;
#pragma unroll
      for (int i = 0; i < 4; ++i) {
        const int srow = s0 + wm + i * 16 + quad * 4;
#pragma unroll
        for (int r = 0; r < 4; ++r)
          v[baseT + srow + r] = f2b(acc[i][j][r] + bias);
      }
    } else {
      u16* outp = (region == 0) ? q : kk;
      const float mult = (region == 0) ? QS : 1.0f;
      const size_t base = ((size_t)(hb + hh) * 2048) * 64 + dh;
#pragma unroll
      for (int i = 0; i < 4; ++i) {
        const int srow = s0 + wm + i * 16 + quad * 4;
#pragma unroll
        for (int r = 0; r < 4; ++r)
          outp[base + (size_t)(srow + r) * 64] = f2b((acc[i][j][r] + bias) * mult);
      }
    }
  }
}

// ---------------- K2: flash attention, R15 loop @ 5 blocks/CU ----------------
// R20: R19 post-mortem: 6 blocks/CU came at the cost of the double-buffer ->
// serial stage->vmcnt(0)->compute stall every iter (the R8 pathology) + 2x
// staging ops; dur 130->156 despite occupancy 36->52. R18: VGPR cap 32 ->
// spill. Lesson: occupancy must rise with the dbuf intact and VGPR >= ~64.
// This round: R15's exact loop (128-row q-tiles, K/V double-buffer, 1
// barrier/iter, MFMA row-sum, defer-max, pk2), but the 8KB LDS mask row is
// replaced by per-iter int4 mask loads from global (R10/R11-validated:
// issued BEFORE stage with sched_barrier(0) pin -> consumption waits
// vmcnt(4), never a drain; measured cost ~4us). LDS 40->32KB ->
// launch_bounds(256,5) = 5 blocks/CU = 20 waves/CU (+25% latency hiding),
// VGPR cap ~102 >> proven 64.
__global__ __launch_bounds__(256, 5) void k_attn(
    const u16* __restrict__ q, const u16* __restrict__ k,
    const u16* __restrict__ v, const int* __restrict__ mask,
    u16* __restrict__ attn, int b_fixed) {
  __shared__ __align__(16) u16 Ksm[2][64 * 64];  // 16KB double-buffered
  __shared__ __align__(16) u16 Vsm[2][64 * 64];  // 16KB double-buffered
  const int bid = blockIdx.x;
  const int tid = threadIdx.x, wave = tid >> 6, lane = tid & 63;
  const int col = lane & 15, quad = lane >> 4;
  int qblk, h, b, hb;
  if (b_fixed < 0) {
    // work id w: group w>>4 = (b,h); all 16 q-blocks of a group on one XCD
    const int w = ((bid & 7) << 7) | (bid >> 3);
    qblk = w & 15; h = (w >> 4) & 15; b = w >> 8; hb = b * 16 + h;
  } else {
    qblk = bid & 15; h = bid >> 4; b = b_fixed; hb = h;
  }
  const size_t bh = (size_t)hb * 2048 * 64;
  const int* mrow = mask + b * 2048;

  bf16x8 qf[2][2];
#pragma unroll
  for (int qt = 0; qt < 2; ++qt)
#pragma unroll
    for (int c = 0; c < 2; ++c)
      qf[qt][c] = *(const bf16x8*)(q + bh +
                   (size_t)(qblk * 128 + wave * 32 + qt * 16 + col) * 64 + c * 32 + quad * 8);

  const int r8 = lane >> 3, chn = lane & 7;
  const int g = chn ^ r8;
  const int swz = col & 7;

  // cooperative stage of one 64-key K/V tile into buffer `buf`
  auto STAGE = [&](int buf, int kt) {
#pragma unroll
    for (int s = 0; s < 2; ++s) {
      const int row = (wave * 2 + s) * 8 + r8;
      gld16(k + bh + (size_t)(kt * 64 + row) * 64 + g * 8,
            (char*)Ksm[buf] + (wave * 2 + s) * 1024);
      gld16(v + bh + (size_t)row * 2048 + kt * 64 + g * 8,
            (char*)Vsm[buf] + (wave * 2 + s) * 1024);
    }
  };

  f32x4 o[2][4];
#pragma unroll
  for (int qt = 0; qt < 2; ++qt)
#pragma unroll
    for (int n = 0; n < 4; ++n) o[qt][n] = f32x4{0.f, 0.f, 0.f, 0.f};
  f32x4 lacc[2] = {f32x4{0.f, 0.f, 0.f, 0.f}, f32x4{0.f, 0.f, 0.f, 0.f}};
  float mrun[2] = {-1e30f, -1e30f};
  const bf16x4s vones = {0x3F80, 0x3F80, 0x3F80, 0x3F80};  // bf16 1.0 x4

  // prologue: stage kt=0 into buffer 0
  STAGE(0, 0);
  asm volatile("s_waitcnt vmcnt(0)" ::: "memory");
  __syncthreads();

  int cur = 0;
  for (int kt = 0; kt < 32; ++kt) {
    // mask words FIRST (so their consumption waits vmcnt(4), not a drain)
    f32x4 mb[4];
#pragma unroll
    for (int mt = 0; mt < 4; ++mt) {
      const int4 mi = *(const int4*)(mrow + kt * 64 + mt * 16 + quad * 4);
      mb[mt][0] = (mi.x != 0) ? -1e30f : 0.f;
      mb[mt][1] = (mi.y != 0) ? -1e30f : 0.f;
      mb[mt][2] = (mi.z != 0) ? -1e30f : 0.f;
      mb[mt][3] = (mi.w != 0) ? -1e30f : 0.f;
    }
    __builtin_amdgcn_sched_barrier(0);  // pin: mask loads before stage loads
    if (kt < 31) STAGE(cur ^ 1, kt + 1);

    // ---- QK: mt-outer, mask bias as C-init ----
    f32x4 sc[2][4];  // [qt][mt]
    __builtin_amdgcn_s_setprio(1);
#pragma unroll
    for (int mt = 0; mt < 4; ++mt) {
      const bf16x8 ka0 = *(const bf16x8*)((const char*)Ksm[cur] +
          (mt * 16 + col) * 128 + (quad ^ swz) * 16);
      const bf16x8 ka1 = *(const bf16x8*)((const char*)Ksm[cur] +
          (mt * 16 + col) * 128 + ((4 + quad) ^ swz) * 16);
#pragma unroll
      for (int qt = 0; qt < 2; ++qt) {
        f32x4 z = mb[mt];
        z = __builtin_amdgcn_mfma_f32_16x16x32_bf16(ka0, qf[qt][0], z, 0, 0, 0);
        sc[qt][mt] = __builtin_amdgcn_mfma_f32_16x16x32_bf16(ka1, qf[qt][1], z, 0, 0, 0);
      }
    }
    __builtin_amdgcn_s_setprio(0);

    // ---- online softmax with defer-max; P packed in-register via pk2 ----
    float alpha[2];
    int resc[2];
    bf16x4s pa[2][4];  // [qt][mt]: P[q=col][key=quad*4+j] -- matches sc layout
#pragma unroll
    for (int qt = 0; qt < 2; ++qt) {
      float tm = fmaxf(fmaxf(sc[qt][0][0], sc[qt][0][1]),
                       fmaxf(sc[qt][0][2], sc[qt][0][3]));
#pragma unroll
      for (int mt = 1; mt < 4; ++mt)
#pragma unroll
        for (int r = 0; r < 4; ++r) tm = fmaxf(tm, sc[qt][mt][r]);
      tm = fmaxf(tm, __shfl_xor(tm, 16, 64));
      tm = fmaxf(tm, __shfl_xor(tm, 32, 64));
      resc[qt] = __any(tm > mrun[qt]);
      if (resc[qt]) {  // wave-uniform branch
        const float mnew = fmaxf(mrun[qt], tm);
        alpha[qt] = __builtin_amdgcn_exp2f(mrun[qt] - mnew);
        mrun[qt] = mnew;
      } else {
        alpha[qt] = 1.0f;  // exact: mnew == mrun
      }
#pragma unroll
      for (int mt = 0; mt < 4; ++mt) {
#pragma unroll
        for (int r = 0; r < 4; ++r)
          sc[qt][mt][r] = __builtin_amdgcn_exp2f(sc[qt][mt][r] - mrun[qt]);
        uint2 w;
        w.x = pk2(sc[qt][mt][0], sc[qt][mt][1]);
        w.y = pk2(sc[qt][mt][2], sc[qt][mt][3]);
        pa[qt][mt] = __builtin_bit_cast(bf16x4s, w);
      }
    }

    // ---- conditional o/l-rescale (skipped in most iterations) ----
    if (resc[0] | resc[1]) {
      float ar[2][4];
#pragma unroll
      for (int qt = 0; qt < 2; ++qt)
#pragma unroll
        for (int r = 0; r < 4; ++r) ar[qt][r] = __shfl(alpha[qt], quad * 4 + r, 64);
#pragma unroll
      for (int qt = 0; qt < 2; ++qt) {
#pragma unroll
        for (int nt = 0; nt < 4; ++nt)
#pragma unroll
          for (int r = 0; r < 4; ++r) o[qt][nt][r] *= ar[qt][r];
#pragma unroll
        for (int r = 0; r < 4; ++r) lacc[qt][r] *= ar[qt][r];
      }
    }

    // ---- PV: K=16 MFMAs, V fragments as ds_read_b64 (keys quad*4..+3) ----
    __builtin_amdgcn_s_setprio(1);
#pragma unroll
    for (int nt = 0; nt < 4; ++nt) {
      bf16x4s vb[4];
#pragma unroll
      for (int mt = 0; mt < 4; ++mt) {
        // Vsm row = dh = nt*16+col; stored 16B-chunk p holds keys (p^swz)*8
        const uint2 raw = *(const uint2*)((const char*)Vsm[cur] +
            (nt * 16 + col) * 128 + (((mt * 2 + (quad >> 1)) ^ swz) << 4) +
            ((quad & 1) << 3));
        vb[mt] = __builtin_bit_cast(bf16x4s, raw);
      }
#pragma unroll
      for (int qt = 0; qt < 2; ++qt) {
        f32x4 t = o[qt][nt];
#pragma unroll
        for (int mt = 0; mt < 4; ++mt) t = mfma16(pa[qt][mt], vb[mt], t);
        o[qt][nt] = t;
      }
    }
    // row-sum via MFMA: lacc[qt] += P . ones  (B=ones => layout-independent)
#pragma unroll
    for (int qt = 0; qt < 2; ++qt)
#pragma unroll
      for (int mt = 0; mt < 4; ++mt)
        lacc[qt] = mfma16(pa[qt][mt], vones, lacc[qt]);
    __builtin_amdgcn_s_setprio(0);

    // next-tile loads were issued ~one full compute phase ago
    asm volatile("s_waitcnt vmcnt(0)" ::: "memory");
    __syncthreads();
    cur ^= 1;
  }

  const int arow0 = (b_fixed < 0) ? b * 2048 : 0;
#pragma unroll
  for (int qt = 0; qt < 2; ++qt) {
    float inv[4];
#pragma unroll
    for (int r = 0; r < 4; ++r) inv[r] = 1.0f / lacc[qt][r];
#pragma unroll
    for (int n = 0; n < 4; ++n)
#pragma unroll
      for (int r = 0; r < 4; ++r) {
        const int srow = qblk * 128 + wave * 32 + qt * 16 + quad * 4 + r;
        const size_t idx = ((size_t)(arow0 + srow)) * 1024 + h * 64 + n * 16 + col;
        attn[idx] = f2b(o[qt][n][r] * inv[r]);
      }
  }
}

// ---------------- K3a: output projection, all-bf16 staging ----------------
__global__ __launch_bounds__(256, 2) void k_proj_a(
    const u16* __restrict__ attn, const u16* __restrict__ wb,
    const float* __restrict__ bproj, float* __restrict__ out) {
  __shared__ __align__(16) u16 Asm[128 * 32];
  __shared__ __align__(16) u16 Bsm[128 * 32];
  const int bn = blockIdx.x;  // 0..7
  const int bm = blockIdx.y;  // 0..63
  const int tid = threadIdx.x;
  const int wave = tid >> 6, lane = tid & 63;
  const int col = lane & 15, quad = lane >> 4;
  const int b = bm >> 4;
  const int s0 = (bm & 15) * 128;
  const int c0 = wave * 2;
  const int srow0 = c0 * 16 + (lane >> 2);
  const int kc = (lane & 3) * 8;
  const u16* gA0 = attn + (size_t)(bm * 128 + srow0) * 1024 + kc;
  const u16* gA1 = attn + (size_t)(bm * 128 + srow0 + 16) * 1024 + kc;
  const u16* gB0 = wb + (size_t)(bn * 128 + srow0) * 1024 + kc;
  const u16* gB1 = wb + (size_t)(bn * 128 + srow0 + 16) * 1024 + kc;
  u16* lA0 = Asm + c0 * 512;
  u16* lA1 = Asm + c0 * 512 + 512;
  u16* lB0 = Bsm + c0 * 512;
  u16* lB1 = Bsm + c0 * 512 + 512;
  const int wm = (wave >> 1) * 64, wn = (wave & 1) * 64;

  f32x4 acc[4][4];
#pragma unroll
  for (int i = 0; i < 4; ++i)
#pragma unroll
    for (int j = 0; j < 4; ++j) acc[i][j] = f32x4{0.f, 0.f, 0.f, 0.f};

  for (int k0 = 0; k0 < 1024; k0 += 32) {
    __syncthreads();
    gld16(gA0 + k0, lA0);
    gld16(gA1 + k0, lA1);
    gld16(gB0 + k0, lB0);
    gld16(gB1 + k0, lB1);
    __builtin_amdgcn_s_waitcnt(0);
    __syncthreads();
    bf16x8 af[4], bfr[4];
#pragma unroll
    for (int i = 0; i < 4; ++i)
      af[i] = *(const bf16x8*)(Asm + (wm + i * 16 + col) * 32 + quad * 8);
#pragma unroll
    for (int j = 0; j < 4; ++j)
      bfr[j] = *(const bf16x8*)(Bsm + (wn + j * 16 + col) * 32 + quad * 8);
#pragma unroll
    for (int i = 0; i < 4; ++i)
#pragma unroll
      for (int j = 0; j < 4; ++j)
        acc[i][j] = __builtin_amdgcn_mfma_f32_16x16x32_bf16(af[i], bfr[j], acc[i][j], 0, 0, 0);
  }

#pragma unroll
  for (int j = 0; j < 4; ++j) {
    const int n = bn * 128 + wn + j * 16 + col;
    const float bias = bproj[n];
#pragma unroll
    for (int i = 0; i < 4; ++i) {
      const int srow = s0 + wm + i * 16 + quad * 4;
#pragma unroll
      for (int r = 0; r < 4; ++r)
        out[(size_t)((srow + r) * 4 + b) * 1024 + n] = acc[i][j][r] + bias;
    }
  }
}

// ---------------- K3b: output projection, inline-convert B (fallback) ----------------
__global__ __launch_bounds__(256, 2) void k_proj_f32(
    const u16* __restrict__ attn, const float* __restrict__ Wproj,
    const float* __restrict__ bproj, float* __restrict__ out, int b_fixed) {
  __shared__ __align__(16) u16 Asm[128 * 32];
  __shared__ __align__(16) u16 Bsm[128 * 32];
  const int bn = blockIdx.x;
  const int bm = blockIdx.y;
  const int tid = threadIdx.x;
  const int wave = tid >> 6, lane = tid & 63;
  const int col = lane & 15, quad = lane >> 4;
  int b, s0;
  if (b_fixed < 0) { b = bm >> 4; s0 = (bm & 15) * 128; }
  else             { b = b_fixed; s0 = bm * 128; }

  const int c0 = wave * 2;
  const int srow0 = c0 * 16 + (lane >> 2);
  const int kc = (lane & 3) * 8;
  const u16* gA0 = attn + (size_t)(bm * 128 + srow0) * 1024 + kc;
  const u16* gA1 = attn + (size_t)(bm * 128 + srow0 + 16) * 1024 + kc;
  u16* lA0 = Asm + c0 * 512;
  u16* lA1 = Asm + c0 * 512 + 512;
  const int brow = tid >> 1;
  const int kseg = (tid & 1) * 16;
  const float* gB = Wproj + (size_t)(bn * 128 + brow) * 1024 + kseg;
  u16* lB = Bsm + brow * 32 + kseg;
  const int wm = (wave >> 1) * 64, wn = (wave & 1) * 64;

  f32x4 acc[4][4];
#pragma unroll
  for (int i = 0; i < 4; ++i)
#pragma unroll
    for (int j = 0; j < 4; ++j) acc[i][j] = f32x4{0.f, 0.f, 0.f, 0.f};

  for (int k0 = 0; k0 < 1024; k0 += 32) {
    float4 bv[4];
#pragma unroll
    for (int u = 0; u < 4; ++u) bv[u] = *(const float4*)(gB + k0 + u * 4);
    __syncthreads();
    gld16(gA0 + k0, lA0);
    gld16(gA1 + k0, lA1);
    cvt16_store(bv, lB);
    __builtin_amdgcn_s_waitcnt(0);
    __syncthreads();
    bf16x8 af[4], bfr[4];
#pragma unroll
    for (int i = 0; i < 4; ++i)
      af[i] = *(const bf16x8*)(Asm + (wm + i * 16 + col) * 32 + quad * 8);
#pragma unroll
    for (int j = 0; j < 4; ++j)
      bfr[j] = *(const bf16x8*)(Bsm + (wn + j * 16 + col) * 32 + quad * 8);
#pragma unroll
    for (int i = 0; i < 4; ++i)
#pragma unroll
      for (int j = 0; j < 4; ++j)
        acc[i][j] = __builtin_amdgcn_mfma_f32_16x16x32_bf16(af[i], bfr[j], acc[i][j], 0, 0, 0);
  }

#pragma unroll
  for (int j = 0; j < 4; ++j) {
    const int n = bn * 128 + wn + j * 16 + col;
    const float bias = bproj[n];
#pragma unroll
    for (int i = 0; i < 4; ++i) {
      const int srow = s0 + wm + i * 16 + quad * 4;
#pragma unroll
      for (int r = 0; r < 4; ++r)
        out[(size_t)((srow + r) * 4 + b) * 1024 + n] = acc[i][j][r] + bias;
    }
  }
}

extern "C" void kernel_launch(void* const* d_in, const int* in_sizes, int n_in,
                              void* d_out, int out_size, void* d_ws, size_t ws_size,
                              hipStream_t stream) {
  const float* inp = (const float*)d_in[0];
  const int* mask = (const int*)d_in[1];
  const float* Wqkv = (const float*)d_in[2];
  const float* bqkv = (const float*)d_in[3];
  const float* Wproj = (const float*)d_in[4];
  const float* bproj = (const float*)d_in[5];
  float* out = (float*)d_out;

  const size_t FULLSZ = (size_t)BATCH * NHEAD * SEQ * DHEAD;  // 8388608 elems
  const size_t WQKV_E = (size_t)3 * DIM * DIM;                // 3145728
  const size_t WPROJ_E = (size_t)DIM * DIM;                   // 1048576
  const size_t pathA_bytes = (4 * FULLSZ + WQKV_E + WPROJ_E) * sizeof(u16);  // 75.5 MB

  if (ws_size >= pathA_bytes) {
    // Path A: convert-once + all-async-bf16 GEMMs.
    u16* q = (u16*)d_ws;
    u16* kk = q + FULLSZ;
    u16* v = kk + FULLSZ;
    u16* xb = v + FULLSZ;      // converted inp; later overwritten as attn buffer
    u16* attn = xb;            // alias — k_attn writes after k_qkv_a finished reading
    u16* wqkvb = xb + FULLSZ;
    u16* wprojb = wqkvb + WQKV_E;
    k_cvt<<<dim3(12288), 256, 0, stream>>>(inp, Wqkv, Wproj, xb, wqkvb, wprojb);
    k_qkv_a<<<dim3(24, 64), 256, 0, stream>>>(xb, wqkvb, bqkv, q, kk, v);
    k_attn<<<dim3(1024), 256, 0, stream>>>(q, kk, v, mask, attn, -1);
    k_proj_a<<<dim3(8, 64), 256, 0, stream>>>(attn, wprojb, bproj, out);
  } else if (ws_size >= 4 * FULLSZ * sizeof(u16)) {
    // Path B: proven R5 pipeline (inline f32 convert).
    u16* q = (u16*)d_ws;
    u16* kk = q + FULLSZ;
    u16* v = kk + FULLSZ;
    u16* attn = v + FULLSZ;
    k_qkv_f32<<<dim3(24, 64), 256, 0, stream>>>(inp, Wqkv, bqkv, q, kk, v, -1);
    k_attn<<<dim3(1024), 256, 0, stream>>>(q, kk, v, mask, attn, -1);
    k_proj_f32<<<dim3(8, 64), 256, 0, stream>>>(attn, Wproj, bproj, out, -1);
  } else {
    // Path C: per-batch pipeline, 16 MiB workspace.
    const size_t BSZ = (size_t)NHEAD * SEQ * DHEAD;
    u16* q = (u16*)d_ws;
    u16* kk = q + BSZ;
    u16* v = kk + BSZ;
    u16* attn = v + BSZ;
    for (int b = 0; b < BATCH; ++b) {
      k_qkv_f32<<<dim3(24, 16), 256, 0, stream>>>(inp, Wqkv, bqkv, q, kk, v, b);
      k_attn<<<dim3(256), 256, 0, stream>>>(q, kk, v, mask, attn, b);
      k_proj_f32<<<dim3(8, 16), 256, 0, stream>>>(attn, Wproj, bproj, out, b);
    }
  }
}

// Round 13
// 340.280 us; speedup vs baseline: 1.5518x; 1.5518x over previous
//
#include <hip/hip_runtime.h>

#define SEQ 2048
#define BATCH 4
#define DIM 1024
#define NHEAD 16
#define DHEAD 64

typedef __bf16 bf16;
typedef __bf16 bf16x8 __attribute__((ext_vector_type(8)));
typedef short bf16x4s __attribute__((ext_vector_type(4)));
typedef float f32x4 __attribute__((ext_vector_type(4)));
typedef unsigned int u32x4 __attribute__((ext_vector_type(4)));
typedef unsigned short u16;
typedef unsigned int u32;

__device__ __forceinline__ void gld16(const void* g, void* l) {
  __builtin_amdgcn_global_load_lds((__attribute__((address_space(1))) void*)(void*)g,
                                   (__attribute__((address_space(3))) void*)l, 16, 0, 0);
}

__device__ __forceinline__ u16 f2b(float f) {  // fp32 -> bf16 bits, RNE
  u32 u = __builtin_bit_cast(u32, f);
  u32 r = (u + 0x7FFFu + ((u >> 16) & 1u)) >> 16;
  return (u16)r;
}

// pack two f32 -> (bf16(f1)<<16)|bf16(f0), round-half-up (==RNE except exact ties)
__device__ __forceinline__ u32 pk2(float f0, float f1) {
  const u32 a = __builtin_bit_cast(u32, f1) + 0x8000u;
  const u32 b = __builtin_bit_cast(u32, f0) + 0x8000u;
  return __builtin_amdgcn_perm(a, b, 0x07060302u);
}

// K=16 bf16 MFMA: A/B = 4 bf16 (2 VGPR), layout A[m=lane&15][k=quad*4+j]
__device__ __forceinline__ f32x4 mfma16(bf16x4s a, bf16x4s b, f32x4 c) {
#if __has_builtin(__builtin_amdgcn_mfma_f32_16x16x16bf16_1k)
  return __builtin_amdgcn_mfma_f32_16x16x16bf16_1k(a, b, c, 0, 0, 0);
#else
  asm volatile("v_mfma_f32_16x16x16_bf16 %0, %1, %2, %0"
               : "+v"(c) : "v"(a), "v"(b));
  return c;
#endif
}

__device__ __forceinline__ void cvt16_store(const float4 v[4], u16* dst) {
  union { u16 h[16]; uint4 q[2]; } pk;
#pragma unroll
  for (int j = 0; j < 4; ++j) {
    pk.h[j * 4 + 0] = f2b(v[j].x);
    pk.h[j * 4 + 1] = f2b(v[j].y);
    pk.h[j * 4 + 2] = f2b(v[j].z);
    pk.h[j * 4 + 3] = f2b(v[j].w);
  }
  ((uint4*)dst)[0] = pk.q[0];
  ((uint4*)dst)[1] = pk.q[1];
}

// ---------------- K0: one-shot f32 -> bf16 conversion ----------------
__global__ __launch_bounds__(256) void k_cvt(
    const float* __restrict__ inp, const float* __restrict__ wqkv,
    const float* __restrict__ wproj, u16* __restrict__ xb,
    u16* __restrict__ wqkvb, u16* __restrict__ wprojb) {
  const int idx = blockIdx.x * 256 + threadIdx.x;
  const float4* src;
  u16* dst;
  int off;
  if (idx < 2097152)      { src = (const float4*)inp;   dst = xb;     off = idx; }
  else if (idx < 2883584) { src = (const float4*)wqkv;  dst = wqkvb;  off = idx - 2097152; }
  else                    { src = (const float4*)wproj; dst = wprojb; off = idx - 2883584; }
  const float4 v = src[off];
  union { u16 h[4]; uint2 q; } pk;
  pk.h[0] = f2b(v.x); pk.h[1] = f2b(v.y); pk.h[2] = f2b(v.z); pk.h[3] = f2b(v.w);
  *(uint2*)(dst + (size_t)off * 4) = pk.q;
}

// ---------------- K1a: QKV projection, all-bf16, async staging ----------------
__global__ __launch_bounds__(256, 2) void k_qkv_a(
    const u16* __restrict__ xb, const u16* __restrict__ wb,
    const float* __restrict__ bqkv, u16* __restrict__ q,
    u16* __restrict__ kk, u16* __restrict__ v) {
  __shared__ __align__(16) u16 Asm[128 * 32];
  __shared__ __align__(16) u16 Bsm[128 * 32];
  const int bn = blockIdx.x;   // 0..23
  const int bm = blockIdx.y;   // 0..63
  const int tid = threadIdx.x;
  const int wave = tid >> 6, lane = tid & 63;
  const int col = lane & 15, quad = lane >> 4;
  const int b = bm >> 4;
  const int s0 = (bm & 15) * 128;
  const int c0 = wave * 2;
  const int srow0 = c0 * 16 + (lane >> 2);
  const int kc = (lane & 3) * 8;
  const u16* gA0 = xb + (size_t)((s0 + srow0) * 4 + b) * 1024 + kc;
  const u16* gA1 = xb + (size_t)((s0 + srow0 + 16) * 4 + b) * 1024 + kc;
  const u16* gB0 = wb + (size_t)(bn * 128 + srow0) * 1024 + kc;
  const u16* gB1 = wb + (size_t)(bn * 128 + srow0 + 16) * 1024 + kc;
  u16* lA0 = Asm + c0 * 512;
  u16* lA1 = Asm + c0 * 512 + 512;
  u16* lB0 = Bsm + c0 * 512;
  u16* lB1 = Bsm + c0 * 512 + 512;
  const int wm = (wave >> 1) * 64, wn = (wave & 1) * 64;

  f32x4 acc[4][4];
#pragma unroll
  for (int i = 0; i < 4; ++i)
#pragma unroll
    for (int j = 0; j < 4; ++j) acc[i][j] = f32x4{0.f, 0.f, 0.f, 0.f};

  for (int k0 = 0; k0 < 1024; k0 += 32) {
    __syncthreads();
    gld16(gA0 + k0, lA0);
    gld16(gA1 + k0, lA1);
    gld16(gB0 + k0, lB0);
    gld16(gB1 + k0, lB1);
    __builtin_amdgcn_s_waitcnt(0);
    __syncthreads();
    bf16x8 af[4], bfr[4];
#pragma unroll
    for (int i = 0; i < 4; ++i)
      af[i] = *(const bf16x8*)(Asm + (wm + i * 16 + col) * 32 + quad * 8);
#pragma unroll
    for (int j = 0; j < 4; ++j)
      bfr[j] = *(const bf16x8*)(Bsm + (wn + j * 16 + col) * 32 + quad * 8);
#pragma unroll
    for (int i = 0; i < 4; ++i)
#pragma unroll
      for (int j = 0; j < 4; ++j)
        acc[i][j] = __builtin_amdgcn_mfma_f32_16x16x32_bf16(af[i], bfr[j], acc[i][j], 0, 0, 0);
  }

  const float QS = 0.125f * 1.44269504088896f;  // SCALE * log2(e)
#pragma unroll
  for (int j = 0; j < 4; ++j) {
    const int n = bn * 128 + wn + j * 16 + col;
    const float bias = bqkv[n];
    const int region = n >> 10;  // 0=q 1=k 2=v
    const int hh = (n >> 6) & 15;
    const int dh = n & 63;
    if (region == 2) {  // V transposed: [B,H,DH,S]
      const size_t baseT = ((size_t)(b * 16 + hh) * 64 + dh) * 2048;
#pragma unroll
      for (int i = 0; i < 4; ++i) {
        const int srow = s0 + wm + i * 16 + quad * 4;
#pragma unroll
        for (int r = 0; r < 4; ++r)
          v[baseT + srow + r] = f2b(acc[i][j][r] + bias);
      }
    } else {
      u16* outp = (region == 0) ? q : kk;
      const float mult = (region == 0) ? QS : 1.0f;
      const size_t base = ((size_t)(b * 16 + hh) * 2048) * 64 + dh;
#pragma unroll
      for (int i = 0; i < 4; ++i) {
        const int srow = s0 + wm + i * 16 + quad * 4;
#pragma unroll
        for (int r = 0; r < 4; ++r)
          outp[base + (size_t)(srow + r) * 64] = f2b((acc[i][j][r] + bias) * mult);
      }
    }
  }
}

// ---------------- K1b: QKV projection, f32-inline-convert (fallback) ----------------
__global__ __launch_bounds__(256, 2) void k_qkv_f32(
    const float* __restrict__ inp, const float* __restrict__ Wqkv,
    const float* __restrict__ bqkv, u16* __restrict__ q,
    u16* __restrict__ kk, u16* __restrict__ v, int b_fixed) {
  __shared__ __align__(16) u16 Asm[128 * 32];
  __shared__ __align__(16) u16 Bsm[128 * 32];
  const int bn = blockIdx.x;
  const int bm = blockIdx.y;
  const int tid = threadIdx.x;
  const int wave = tid >> 6, lane = tid & 63;
  const int col = lane & 15, quad = lane >> 4;
  int b, s0, hb;
  if (b_fixed < 0) { b = bm >> 4; s0 = (bm & 15) * 128; hb = b * 16; }
  else             { b = b_fixed; s0 = bm * 128;        hb = 0; }

  const int arow = tid >> 1;
  const int kseg = (tid & 1) * 16;
  const float* gA = inp + (size_t)((s0 + arow) * 4 + b) * 1024 + kseg;
  const float* gB = Wqkv + (size_t)(bn * 128 + arow) * 1024 + kseg;
  u16* lA = Asm + arow * 32 + kseg;
  u16* lB = Bsm + arow * 32 + kseg;
  const int wm = (wave >> 1) * 64, wn = (wave & 1) * 64;

  f32x4 acc[4][4];
#pragma unroll
  for (int i = 0; i < 4; ++i)
#pragma unroll
    for (int j = 0; j < 4; ++j) acc[i][j] = f32x4{0.f, 0.f, 0.f, 0.f};

  for (int k0 = 0; k0 < 1024; k0 += 32) {
    float4 av[4], bv[4];
#pragma unroll
    for (int u = 0; u < 4; ++u) av[u] = *(const float4*)(gA + k0 + u * 4);
#pragma unroll
    for (int u = 0; u < 4; ++u) bv[u] = *(const float4*)(gB + k0 + u * 4);
    __syncthreads();
    cvt16_store(av, lA);
    cvt16_store(bv, lB);
    __syncthreads();
    bf16x8 af[4], bfr[4];
#pragma unroll
    for (int i = 0; i < 4; ++i)
      af[i] = *(const bf16x8*)(Asm + (wm + i * 16 + col) * 32 + quad * 8);
#pragma unroll
    for (int j = 0; j < 4; ++j)
      bfr[j] = *(const bf16x8*)(Bsm + (wn + j * 16 + col) * 32 + quad * 8);
#pragma unroll
    for (int i = 0; i < 4; ++i)
#pragma unroll
      for (int j = 0; j < 4; ++j)
        acc[i][j] = __builtin_amdgcn_mfma_f32_16x16x32_bf16(af[i], bfr[j], acc[i][j], 0, 0, 0);
  }

  const float QS = 0.125f * 1.44269504088896f;
#pragma unroll
  for (int j = 0; j < 4; ++j) {
    const int n = bn * 128 + wn + j * 16 + col;
    const float bias = bqkv[n];
    const int region = n >> 10;
    const int hh = (n >> 6) & 15;
    const int dh = n & 63;
    if (region == 2) {
      const size_t baseT = ((size_t)(hb + hh) * 64 + dh) * 2048;
#pragma unroll
      for (int i = 0; i < 4; ++i) {
        const int srow = s0 + wm + i * 16 + quad * 4;
#pragma unroll
        for (int r = 0; r < 4; ++r)
          v[baseT + srow + r] = f2b(acc[i][j][r] + bias);
      }
    } else {
      u16* outp = (region == 0) ? q : kk;
      const float mult = (region == 0) ? QS : 1.0f;
      const size_t base = ((size_t)(hb + hh) * 2048) * 64 + dh;
#pragma unroll
      for (int i = 0; i < 4; ++i) {
        const int srow = s0 + wm + i * 16 + quad * 4;
#pragma unroll
        for (int r = 0; r < 4; ++r)
          outp[base + (size_t)(srow + r) * 64] = f2b((acc[i][j][r] + bias) * mult);
      }
    }
  }
}

// ---------------- K2: flash attention, 64-row blocks + dbuf @ 5 blocks/CU ----------------
// R21: R20 post-mortem: launch_bounds(256,5) demanded <=102 total regs but
// the 2-qt shape needs ~120 (64 VGPR + ~56 acc) -> allocator squeezed to 48
// and spilled (FETCH 792MB, WRITE 569MB, 343us). Constraint set from
// R18/R19/R20: (a) reg-cap < footprint => spill; (b) no dbuf => serial
// stall; (c) 2-qt footprint ~120 caps at 4 waves/SIMD. Untried feasible
// point: HALVE per-wave state (single 16-row q-tile/wave, ~80-90 total
// regs, shape validated R18/R19) while KEEPING the dbuf: 64-row q-blocks,
// grid 2048, Ksm[2]+Vsm[2] = 32KB exactly, mask via per-iter global int4
// (R11/R20-validated). launch_bounds(256,4) = cap 128, NO forced squeeze;
// occupancy from LDS: 160/32 = 5 blocks/CU = 20 waves/CU (reg footprint
// fits 512/5). R19 proved doubled K/V re-staging is L2-absorbed (FETCH
// unchanged 24.6MB).
// Keeps: MFMA row-sum (R15), defer-max (R12), in-reg P + pk2 (R11/R12),
// bijective XCD swizzle, K/V dbuf + 1 barrier/iter (R10), setprio.
__global__ __launch_bounds__(256, 4) void k_attn(
    const u16* __restrict__ q, const u16* __restrict__ k,
    const u16* __restrict__ v, const int* __restrict__ mask,
    u16* __restrict__ attn, int b_fixed) {
  __shared__ __align__(16) u16 Ksm[2][64 * 64];  // 16KB double-buffered
  __shared__ __align__(16) u16 Vsm[2][64 * 64];  // 16KB double-buffered
  const int bid = blockIdx.x;
  const int tid = threadIdx.x, wave = tid >> 6, lane = tid & 63;
  const int col = lane & 15, quad = lane >> 4;
  int qblk, h, b, hb;
  if (b_fixed < 0) {
    // w = xcd*256 + idx (bijective, grid 2048); all 32 q-blocks of a (b,h)
    // group land on one XCD (8 groups per XCD).
    const int w = ((bid & 7) << 8) | (bid >> 3);
    qblk = w & 31; h = (w >> 5) & 15; b = w >> 9; hb = b * 16 + h;
  } else {
    qblk = bid & 31; h = bid >> 5; b = b_fixed; hb = h;
  }
  const size_t bh = (size_t)hb * 2048 * 64;
  const int* mrow = mask + b * 2048;

  // each wave owns one 16-row q tile: rows qblk*64 + wave*16 .. +15
  bf16x8 qf[2];
#pragma unroll
  for (int c = 0; c < 2; ++c)
    qf[c] = *(const bf16x8*)(q + bh +
                 (size_t)(qblk * 64 + wave * 16 + col) * 64 + c * 32 + quad * 8);

  const int r8 = lane >> 3, chn = lane & 7;
  const int g = chn ^ r8;
  const int swz = col & 7;

  // cooperative stage: 4 waves x 16 rows each (2 gld16 K + 2 gld16 V)
  auto STAGE = [&](int buf, int kt) {
#pragma unroll
    for (int s = 0; s < 2; ++s) {
      const int row = wave * 16 + s * 8 + r8;
      gld16(k + bh + (size_t)(kt * 64 + row) * 64 + g * 8,
            (char*)Ksm[buf] + (wave * 16 + s * 8) * 128);
      gld16(v + bh + (size_t)row * 2048 + kt * 64 + g * 8,
            (char*)Vsm[buf] + (wave * 16 + s * 8) * 128);
    }
  };

  f32x4 o[4];
#pragma unroll
  for (int n = 0; n < 4; ++n) o[n] = f32x4{0.f, 0.f, 0.f, 0.f};
  f32x4 lacc = f32x4{0.f, 0.f, 0.f, 0.f};
  float mrun = -1e30f;
  const bf16x4s vones = {0x3F80, 0x3F80, 0x3F80, 0x3F80};  // bf16 1.0 x4

  // prologue: stage kt=0 into buffer 0
  STAGE(0, 0);
  asm volatile("s_waitcnt vmcnt(0)" ::: "memory");
  __syncthreads();

  int cur = 0;
  for (int kt = 0; kt < 32; ++kt) {
    // mask words FIRST (so their consumption waits vmcnt(4), not a drain)
    f32x4 mb[4];
#pragma unroll
    for (int mt = 0; mt < 4; ++mt) {
      const int4 mi = *(const int4*)(mrow + kt * 64 + mt * 16 + quad * 4);
      mb[mt][0] = (mi.x != 0) ? -1e30f : 0.f;
      mb[mt][1] = (mi.y != 0) ? -1e30f : 0.f;
      mb[mt][2] = (mi.z != 0) ? -1e30f : 0.f;
      mb[mt][3] = (mi.w != 0) ? -1e30f : 0.f;
    }
    __builtin_amdgcn_sched_barrier(0);  // pin: mask loads before stage loads
    if (kt < 31) STAGE(cur ^ 1, kt + 1);

    // ---- QK: mask bias as C-init ----
    f32x4 sc[4];  // [mt]
    __builtin_amdgcn_s_setprio(1);
#pragma unroll
    for (int mt = 0; mt < 4; ++mt) {
      const bf16x8 ka0 = *(const bf16x8*)((const char*)Ksm[cur] +
          (mt * 16 + col) * 128 + (quad ^ swz) * 16);
      const bf16x8 ka1 = *(const bf16x8*)((const char*)Ksm[cur] +
          (mt * 16 + col) * 128 + ((4 + quad) ^ swz) * 16);
      f32x4 z = mb[mt];
      z = __builtin_amdgcn_mfma_f32_16x16x32_bf16(ka0, qf[0], z, 0, 0, 0);
      sc[mt] = __builtin_amdgcn_mfma_f32_16x16x32_bf16(ka1, qf[1], z, 0, 0, 0);
    }
    __builtin_amdgcn_s_setprio(0);

    // ---- online softmax with defer-max; P packed in-register via pk2 ----
    float tm = fmaxf(fmaxf(sc[0][0], sc[0][1]), fmaxf(sc[0][2], sc[0][3]));
#pragma unroll
    for (int mt = 1; mt < 4; ++mt)
#pragma unroll
      for (int r = 0; r < 4; ++r) tm = fmaxf(tm, sc[mt][r]);
    tm = fmaxf(tm, __shfl_xor(tm, 16, 64));
    tm = fmaxf(tm, __shfl_xor(tm, 32, 64));
    const int resc = __any(tm > mrun);
    float alpha;
    if (resc) {  // wave-uniform branch
      const float mnew = fmaxf(mrun, tm);
      alpha = __builtin_amdgcn_exp2f(mrun - mnew);
      mrun = mnew;
    } else {
      alpha = 1.0f;  // exact: mnew == mrun
    }
    bf16x4s pa[4];  // [mt]: P[q=col][key=quad*4+j] -- matches sc layout
#pragma unroll
    for (int mt = 0; mt < 4; ++mt) {
#pragma unroll
      for (int r = 0; r < 4; ++r)
        sc[mt][r] = __builtin_amdgcn_exp2f(sc[mt][r] - mrun);
      uint2 w;
      w.x = pk2(sc[mt][0], sc[mt][1]);
      w.y = pk2(sc[mt][2], sc[mt][3]);
      pa[mt] = __builtin_bit_cast(bf16x4s, w);
    }

    // ---- conditional o/l-rescale (skipped in most iterations) ----
    if (resc) {
      float ar[4];
#pragma unroll
      for (int r = 0; r < 4; ++r) ar[r] = __shfl(alpha, quad * 4 + r, 64);
#pragma unroll
      for (int nt = 0; nt < 4; ++nt)
#pragma unroll
        for (int r = 0; r < 4; ++r) o[nt][r] *= ar[r];
#pragma unroll
      for (int r = 0; r < 4; ++r) lacc[r] *= ar[r];
    }

    // ---- PV: K=16 MFMAs, V fragments as ds_read_b64 (keys quad*4..+3) ----
    __builtin_amdgcn_s_setprio(1);
#pragma unroll
    for (int nt = 0; nt < 4; ++nt) {
      bf16x4s vb[4];
#pragma unroll
      for (int mt = 0; mt < 4; ++mt) {
        // Vsm row = dh = nt*16+col; stored 16B-chunk p holds keys (p^swz)*8
        const uint2 raw = *(const uint2*)((const char*)Vsm[cur] +
            (nt * 16 + col) * 128 + (((mt * 2 + (quad >> 1)) ^ swz) << 4) +
            ((quad & 1) << 3));
        vb[mt] = __builtin_bit_cast(bf16x4s, raw);
      }
      f32x4 t = o[nt];
#pragma unroll
      for (int mt = 0; mt < 4; ++mt) t = mfma16(pa[mt], vb[mt], t);
      o[nt] = t;
    }
    // row-sum via MFMA: lacc += P . ones  (B=ones => layout-independent)
#pragma unroll
    for (int mt = 0; mt < 4; ++mt)
      lacc = mfma16(pa[mt], vones, lacc);
    __builtin_amdgcn_s_setprio(0);

    // next-tile loads were issued ~one full compute phase ago
    asm volatile("s_waitcnt vmcnt(0)" ::: "memory");
    __syncthreads();
    cur ^= 1;
  }

  const int arow0 = (b_fixed < 0) ? b * 2048 : 0;
  float inv[4];
#pragma unroll
  for (int r = 0; r < 4; ++r) inv[r] = 1.0f / lacc[r];
#pragma unroll
  for (int n = 0; n < 4; ++n)
#pragma unroll
    for (int r = 0; r < 4; ++r) {
      const int srow = qblk * 64 + wave * 16 + quad * 4 + r;
      const size_t idx = ((size_t)(arow0 + srow)) * 1024 + h * 64 + n * 16 + col;
      attn[idx] = f2b(o[n][r] * inv[r]);
    }
}

// ---------------- K3a: output projection, all-bf16 staging ----------------
__global__ __launch_bounds__(256, 2) void k_proj_a(
    const u16* __restrict__ attn, const u16* __restrict__ wb,
    const float* __restrict__ bproj, float* __restrict__ out) {
  __shared__ __align__(16) u16 Asm[128 * 32];
  __shared__ __align__(16) u16 Bsm[128 * 32];
  const int bn = blockIdx.x;  // 0..7
  const int bm = blockIdx.y;  // 0..63
  const int tid = threadIdx.x;
  const int wave = tid >> 6, lane = tid & 63;
  const int col = lane & 15, quad = lane >> 4;
  const int b = bm >> 4;
  const int s0 = (bm & 15) * 128;
  const int c0 = wave * 2;
  const int srow0 = c0 * 16 + (lane >> 2);
  const int kc = (lane & 3) * 8;
  const u16* gA0 = attn + (size_t)(bm * 128 + srow0) * 1024 + kc;
  const u16* gA1 = attn + (size_t)(bm * 128 + srow0 + 16) * 1024 + kc;
  const u16* gB0 = wb + (size_t)(bn * 128 + srow0) * 1024 + kc;
  const u16* gB1 = wb + (size_t)(bn * 128 + srow0 + 16) * 1024 + kc;
  u16* lA0 = Asm + c0 * 512;
  u16* lA1 = Asm + c0 * 512 + 512;
  u16* lB0 = Bsm + c0 * 512;
  u16* lB1 = Bsm + c0 * 512 + 512;
  const int wm = (wave >> 1) * 64, wn = (wave & 1) * 64;

  f32x4 acc[4][4];
#pragma unroll
  for (int i = 0; i < 4; ++i)
#pragma unroll
    for (int j = 0; j < 4; ++j) acc[i][j] = f32x4{0.f, 0.f, 0.f, 0.f};

  for (int k0 = 0; k0 < 1024; k0 += 32) {
    __syncthreads();
    gld16(gA0 + k0, lA0);
    gld16(gA1 + k0, lA1);
    gld16(gB0 + k0, lB0);
    gld16(gB1 + k0, lB1);
    __builtin_amdgcn_s_waitcnt(0);
    __syncthreads();
    bf16x8 af[4], bfr[4];
#pragma unroll
    for (int i = 0; i < 4; ++i)
      af[i] = *(const bf16x8*)(Asm + (wm + i * 16 + col) * 32 + quad * 8);
#pragma unroll
    for (int j = 0; j < 4; ++j)
      bfr[j] = *(const bf16x8*)(Bsm + (wn + j * 16 + col) * 32 + quad * 8);
#pragma unroll
    for (int i = 0; i < 4; ++i)
#pragma unroll
      for (int j = 0; j < 4; ++j)
        acc[i][j] = __builtin_amdgcn_mfma_f32_16x16x32_bf16(af[i], bfr[j], acc[i][j], 0, 0, 0);
  }

#pragma unroll
  for (int j = 0; j < 4; ++j) {
    const int n = bn * 128 + wn + j * 16 + col;
    const float bias = bproj[n];
#pragma unroll
    for (int i = 0; i < 4; ++i) {
      const int srow = s0 + wm + i * 16 + quad * 4;
#pragma unroll
      for (int r = 0; r < 4; ++r)
        out[(size_t)((srow + r) * 4 + b) * 1024 + n] = acc[i][j][r] + bias;
    }
  }
}

// ---------------- K3b: output projection, inline-convert B (fallback) ----------------
__global__ __launch_bounds__(256, 2) void k_proj_f32(
    const u16* __restrict__ attn, const float* __restrict__ Wproj,
    const float* __restrict__ bproj, float* __restrict__ out, int b_fixed) {
  __shared__ __align__(16) u16 Asm[128 * 32];
  __shared__ __align__(16) u16 Bsm[128 * 32];
  const int bn = blockIdx.x;
  const int bm = blockIdx.y;
  const int tid = threadIdx.x;
  const int wave = tid >> 6, lane = tid & 63;
  const int col = lane & 15, quad = lane >> 4;
  int b, s0;
  if (b_fixed < 0) { b = bm >> 4; s0 = (bm & 15) * 128; }
  else             { b = b_fixed; s0 = bm * 128; }

  const int c0 = wave * 2;
  const int srow0 = c0 * 16 + (lane >> 2);
  const int kc = (lane & 3) * 8;
  const u16* gA0 = attn + (size_t)(bm * 128 + srow0) * 1024 + kc;
  const u16* gA1 = attn + (size_t)(bm * 128 + srow0 + 16) * 1024 + kc;
  u16* lA0 = Asm + c0 * 512;
  u16* lA1 = Asm + c0 * 512 + 512;
  const int brow = tid >> 1;
  const int kseg = (tid & 1) * 16;
  const float* gB = Wproj + (size_t)(bn * 128 + brow) * 1024 + kseg;
  u16* lB = Bsm + brow * 32 + kseg;
  const int wm = (wave >> 1) * 64, wn = (wave & 1) * 64;

  f32x4 acc[4][4];
#pragma unroll
  for (int i = 0; i < 4; ++i)
#pragma unroll
    for (int j = 0; j < 4; ++j) acc[i][j] = f32x4{0.f, 0.f, 0.f, 0.f};

  for (int k0 = 0; k0 < 1024; k0 += 32) {
    float4 bv[4];
#pragma unroll
    for (int u = 0; u < 4; ++u) bv[u] = *(const float4*)(gB + k0 + u * 4);
    __syncthreads();
    gld16(gA0 + k0, lA0);
    gld16(gA1 + k0, lA1);
    cvt16_store(bv, lB);
    __builtin_amdgcn_s_waitcnt(0);
    __syncthreads();
    bf16x8 af[4], bfr[4];
#pragma unroll
    for (int i = 0; i < 4; ++i)
      af[i] = *(const bf16x8*)(Asm + (wm + i * 16 + col) * 32 + quad * 8);
#pragma unroll
    for (int j = 0; j < 4; ++j)
      bfr[j] = *(const bf16x8*)(Bsm + (wn + j * 16 + col) * 32 + quad * 8);
#pragma unroll
    for (int i = 0; i < 4; ++i)
#pragma unroll
      for (int j = 0; j < 4; ++j)
        acc[i][j] = __builtin_amdgcn_mfma_f32_16x16x32_bf16(af[i], bfr[j], acc[i][j], 0, 0, 0);
  }

#pragma unroll
  for (int j = 0; j < 4; ++j) {
    const int n = bn * 128 + wn + j * 16 + col;
    const float bias = bproj[n];
#pragma unroll
    for (int i = 0; i < 4; ++i) {
      const int srow = s0 + wm + i * 16 + quad * 4;
#pragma unroll
      for (int r = 0; r < 4; ++r)
        out[(size_t)((srow + r) * 4 + b) * 1024 + n] = acc[i][j][r] + bias;
    }
  }
}

extern "C" void kernel_launch(void* const* d_in, const int* in_sizes, int n_in,
                              void* d_out, int out_size, void* d_ws, size_t ws_size,
                              hipStream_t stream) {
  const float* inp = (const float*)d_in[0];
  const int* mask = (const int*)d_in[1];
  const float* Wqkv = (const float*)d_in[2];
  const float* bqkv = (const float*)d_in[3];
  const float* Wproj = (const float*)d_in[4];
  const float* bproj = (const float*)d_in[5];
  float* out = (float*)d_out;

  const size_t FULLSZ = (size_t)BATCH * NHEAD * SEQ * DHEAD;  // 8388608 elems
  const size_t WQKV_E = (size_t)3 * DIM * DIM;                // 3145728
  const size_t WPROJ_E = (size_t)DIM * DIM;                   // 1048576
  const size_t pathA_bytes = (4 * FULLSZ + WQKV_E + WPROJ_E) * sizeof(u16);  // 75.5 MB

  if (ws_size >= pathA_bytes) {
    // Path A: convert-once + all-async-bf16 GEMMs.
    u16* q = (u16*)d_ws;
    u16* kk = q + FULLSZ;
    u16* v = kk + FULLSZ;
    u16* xb = v + FULLSZ;      // converted inp; later overwritten as attn buffer
    u16* attn = xb;            // alias — k_attn writes after k_qkv_a finished reading
    u16* wqkvb = xb + FULLSZ;
    u16* wprojb = wqkvb + WQKV_E;
    k_cvt<<<dim3(12288), 256, 0, stream>>>(inp, Wqkv, Wproj, xb, wqkvb, wprojb);
    k_qkv_a<<<dim3(24, 64), 256, 0, stream>>>(xb, wqkvb, bqkv, q, kk, v);
    k_attn<<<dim3(2048), 256, 0, stream>>>(q, kk, v, mask, attn, -1);
    k_proj_a<<<dim3(8, 64), 256, 0, stream>>>(attn, wprojb, bproj, out);
  } else if (ws_size >= 4 * FULLSZ * sizeof(u16)) {
    // Path B: proven R5 pipeline (inline f32 convert).
    u16* q = (u16*)d_ws;
    u16* kk = q + FULLSZ;
    u16* v = kk + FULLSZ;
    u16* attn = v + FULLSZ;
    k_qkv_f32<<<dim3(24, 64), 256, 0, stream>>>(inp, Wqkv, bqkv, q, kk, v, -1);
    k_attn<<<dim3(2048), 256, 0, stream>>>(q, kk, v, mask, attn, -1);
    k_proj_f32<<<dim3(8, 64), 256, 0, stream>>>(attn, Wproj, bproj, out, -1);
  } else {
    // Path C: per-batch pipeline, 16 MiB workspace.
    const size_t BSZ = (size_t)NHEAD * SEQ * DHEAD;
    u16* q = (u16*)d_ws;
    u16* kk = q + BSZ;
    u16* v = kk + BSZ;
    u16* attn = v + BSZ;
    for (int b = 0; b < BATCH; ++b) {
      k_qkv_f32<<<dim3(24, 16), 256, 0, stream>>>(inp, Wqkv, bqkv, q, kk, v, b);
      k_attn<<<dim3(512), 256, 0, stream>>>(q, kk, v, mask, attn, b);
      k_proj_f32<<<dim3(8, 16), 256, 0, stream>>>(attn, Wproj, bproj, out, b);
    }
  }
}

// Round 14
// 309.703 us; speedup vs baseline: 1.7050x; 1.0987x over previous
//
#include <hip/hip_runtime.h>

#define SEQ 2048
#define BATCH 4
#define DIM 1024
#define NHEAD 16
#define DHEAD 64

typedef __bf16 bf16;
typedef __bf16 bf16x8 __attribute__((ext_vector_type(8)));
typedef short bf16x4s __attribute__((ext_vector_type(4)));
typedef float f32x4 __attribute__((ext_vector_type(4)));
typedef unsigned int u32x4 __attribute__((ext_vector_type(4)));
typedef unsigned short u16;
typedef unsigned int u32;

__device__ __forceinline__ void gld16(const void* g, void* l) {
  __builtin_amdgcn_global_load_lds((__attribute__((address_space(1))) void*)(void*)g,
                                   (__attribute__((address_space(3))) void*)l, 16, 0, 0);
}

__device__ __forceinline__ u16 f2b(float f) {  // fp32 -> bf16 bits, RNE
  u32 u = __builtin_bit_cast(u32, f);
  u32 r = (u + 0x7FFFu + ((u >> 16) & 1u)) >> 16;
  return (u16)r;
}

// pack two f32 -> (bf16(f1)<<16)|bf16(f0), round-half-up (==RNE except exact ties)
__device__ __forceinline__ u32 pk2(float f0, float f1) {
  const u32 a = __builtin_bit_cast(u32, f1) + 0x8000u;
  const u32 b = __builtin_bit_cast(u32, f0) + 0x8000u;
  return __builtin_amdgcn_perm(a, b, 0x07060302u);
}

// K=16 bf16 MFMA: A/B = 4 bf16 (2 VGPR), layout A[m=lane&15][k=quad*4+j]
__device__ __forceinline__ f32x4 mfma16(bf16x4s a, bf16x4s b, f32x4 c) {
#if __has_builtin(__builtin_amdgcn_mfma_f32_16x16x16bf16_1k)
  return __builtin_amdgcn_mfma_f32_16x16x16bf16_1k(a, b, c, 0, 0, 0);
#else
  asm volatile("v_mfma_f32_16x16x16_bf16 %0, %1, %2, %0"
               : "+v"(c) : "v"(a), "v"(b));
  return c;
#endif
}

__device__ __forceinline__ void cvt16_store(const float4 v[4], u16* dst) {
  union { u16 h[16]; uint4 q[2]; } pk;
#pragma unroll
  for (int j = 0; j < 4; ++j) {
    pk.h[j * 4 + 0] = f2b(v[j].x);
    pk.h[j * 4 + 1] = f2b(v[j].y);
    pk.h[j * 4 + 2] = f2b(v[j].z);
    pk.h[j * 4 + 3] = f2b(v[j].w);
  }
  ((uint4*)dst)[0] = pk.q[0];
  ((uint4*)dst)[1] = pk.q[1];
}

// ---------------- K0: one-shot f32 -> bf16 conversion ----------------
__global__ __launch_bounds__(256) void k_cvt(
    const float* __restrict__ inp, const float* __restrict__ wqkv,
    const float* __restrict__ wproj, u16* __restrict__ xb,
    u16* __restrict__ wqkvb, u16* __restrict__ wprojb) {
  const int idx = blockIdx.x * 256 + threadIdx.x;
  const float4* src;
  u16* dst;
  int off;
  if (idx < 2097152)      { src = (const float4*)inp;   dst = xb;     off = idx; }
  else if (idx < 2883584) { src = (const float4*)wqkv;  dst = wqkvb;  off = idx - 2097152; }
  else                    { src = (const float4*)wproj; dst = wprojb; off = idx - 2883584; }
  const float4 v = src[off];
  union { u16 h[4]; uint2 q; } pk;
  pk.h[0] = f2b(v.x); pk.h[1] = f2b(v.y); pk.h[2] = f2b(v.z); pk.h[3] = f2b(v.w);
  *(uint2*)(dst + (size_t)off * 4) = pk.q;
}

// ---------------- K1a: QKV projection, all-bf16, async staging ----------------
__global__ __launch_bounds__(256, 2) void k_qkv_a(
    const u16* __restrict__ xb, const u16* __restrict__ wb,
    const float* __restrict__ bqkv, u16* __restrict__ q,
    u16* __restrict__ kk, u16* __restrict__ v) {
  __shared__ __align__(16) u16 Asm[128 * 32];
  __shared__ __align__(16) u16 Bsm[128 * 32];
  const int bn = blockIdx.x;   // 0..23
  const int bm = blockIdx.y;   // 0..63
  const int tid = threadIdx.x;
  const int wave = tid >> 6, lane = tid & 63;
  const int col = lane & 15, quad = lane >> 4;
  const int b = bm >> 4;
  const int s0 = (bm & 15) * 128;
  const int c0 = wave * 2;
  const int srow0 = c0 * 16 + (lane >> 2);
  const int kc = (lane & 3) * 8;
  const u16* gA0 = xb + (size_t)((s0 + srow0) * 4 + b) * 1024 + kc;
  const u16* gA1 = xb + (size_t)((s0 + srow0 + 16) * 4 + b) * 1024 + kc;
  const u16* gB0 = wb + (size_t)(bn * 128 + srow0) * 1024 + kc;
  const u16* gB1 = wb + (size_t)(bn * 128 + srow0 + 16) * 1024 + kc;
  u16* lA0 = Asm + c0 * 512;
  u16* lA1 = Asm + c0 * 512 + 512;
  u16* lB0 = Bsm + c0 * 512;
  u16* lB1 = Bsm + c0 * 512 + 512;
  const int wm = (wave >> 1) * 64, wn = (wave & 1) * 64;

  f32x4 acc[4][4];
#pragma unroll
  for (int i = 0; i < 4; ++i)
#pragma unroll
    for (int j = 0; j < 4; ++j) acc[i][j] = f32x4{0.f, 0.f, 0.f, 0.f};

  for (int k0 = 0; k0 < 1024; k0 += 32) {
    __syncthreads();
    gld16(gA0 + k0, lA0);
    gld16(gA1 + k0, lA1);
    gld16(gB0 + k0, lB0);
    gld16(gB1 + k0, lB1);
    __builtin_amdgcn_s_waitcnt(0);
    __syncthreads();
    bf16x8 af[4], bfr[4];
#pragma unroll
    for (int i = 0; i < 4; ++i)
      af[i] = *(const bf16x8*)(Asm + (wm + i * 16 + col) * 32 + quad * 8);
#pragma unroll
    for (int j = 0; j < 4; ++j)
      bfr[j] = *(const bf16x8*)(Bsm + (wn + j * 16 + col) * 32 + quad * 8);
#pragma unroll
    for (int i = 0; i < 4; ++i)
#pragma unroll
      for (int j = 0; j < 4; ++j)
        acc[i][j] = __builtin_amdgcn_mfma_f32_16x16x32_bf16(af[i], bfr[j], acc[i][j], 0, 0, 0);
  }

  const float QS = 0.125f * 1.44269504088896f;  // SCALE * log2(e)
#pragma unroll
  for (int j = 0; j < 4; ++j) {
    const int n = bn * 128 + wn + j * 16 + col;
    const float bias = bqkv[n];
    const int region = n >> 10;  // 0=q 1=k 2=v
    const int hh = (n >> 6) & 15;
    const int dh = n & 63;
    if (region == 2) {  // V transposed: [B,H,DH,S]
      const size_t baseT = ((size_t)(b * 16 + hh) * 64 + dh) * 2048;
#pragma unroll
      for (int i = 0; i < 4; ++i) {
        const int srow = s0 + wm + i * 16 + quad * 4;
#pragma unroll
        for (int r = 0; r < 4; ++r)
          v[baseT + srow + r] = f2b(acc[i][j][r] + bias);
      }
    } else {
      u16* outp = (region == 0) ? q : kk;
      const float mult = (region == 0) ? QS : 1.0f;
      const size_t base = ((size_t)(b * 16 + hh) * 2048) * 64 + dh;
#pragma unroll
      for (int i = 0; i < 4; ++i) {
        const int srow = s0 + wm + i * 16 + quad * 4;
#pragma unroll
        for (int r = 0; r < 4; ++r)
          outp[base + (size_t)(srow + r) * 64] = f2b((acc[i][j][r] + bias) * mult);
      }
    }
  }
}

// ---------------- K1b: QKV projection, f32-inline-convert (fallback) ----------------
__global__ __launch_bounds__(256, 2) void k_qkv_f32(
    const float* __restrict__ inp, const float* __restrict__ Wqkv,
    const float* __restrict__ bqkv, u16* __restrict__ q,
    u16* __restrict__ kk, u16* __restrict__ v, int b_fixed) {
  __shared__ __align__(16) u16 Asm[128 * 32];
  __shared__ __align__(16) u16 Bsm[128 * 32];
  const int bn = blockIdx.x;
  const int bm = blockIdx.y;
  const int tid = threadIdx.x;
  const int wave = tid >> 6, lane = tid & 63;
  const int col = lane & 15, quad = lane >> 4;
  int b, s0, hb;
  if (b_fixed < 0) { b = bm >> 4; s0 = (bm & 15) * 128; hb = b * 16; }
  else             { b = b_fixed; s0 = bm * 128;        hb = 0; }

  const int arow = tid >> 1;
  const int kseg = (tid & 1) * 16;
  const float* gA = inp + (size_t)((s0 + arow) * 4 + b) * 1024 + kseg;
  const float* gB = Wqkv + (size_t)(bn * 128 + arow) * 1024 + kseg;
  u16* lA = Asm + arow * 32 + kseg;
  u16* lB = Bsm + arow * 32 + kseg;
  const int wm = (wave >> 1) * 64, wn = (wave & 1) * 64;

  f32x4 acc[4][4];
#pragma unroll
  for (int i = 0; i < 4; ++i)
#pragma unroll
    for (int j = 0; j < 4; ++j) acc[i][j] = f32x4{0.f, 0.f, 0.f, 0.f};

  for (int k0 = 0; k0 < 1024; k0 += 32) {
    float4 av[4], bv[4];
#pragma unroll
    for (int u = 0; u < 4; ++u) av[u] = *(const float4*)(gA + k0 + u * 4);
#pragma unroll
    for (int u = 0; u < 4; ++u) bv[u] = *(const float4*)(gB + k0 + u * 4);
    __syncthreads();
    cvt16_store(av, lA);
    cvt16_store(bv, lB);
    __syncthreads();
    bf16x8 af[4], bfr[4];
#pragma unroll
    for (int i = 0; i < 4; ++i)
      af[i] = *(const bf16x8*)(Asm + (wm + i * 16 + col) * 32 + quad * 8);
#pragma unroll
    for (int j = 0; j < 4; ++j)
      bfr[j] = *(const bf16x8*)(Bsm + (wn + j * 16 + col) * 32 + quad * 8);
#pragma unroll
    for (int i = 0; i < 4; ++i)
#pragma unroll
      for (int j = 0; j < 4; ++j)
        acc[i][j] = __builtin_amdgcn_mfma_f32_16x16x32_bf16(af[i], bfr[j], acc[i][j], 0, 0, 0);
  }

  const float QS = 0.125f * 1.44269504088896f;
#pragma unroll
  for (int j = 0; j < 4; ++j) {
    const int n = bn * 128 + wn + j * 16 + col;
    const float bias = bqkv[n];
    const int region = n >> 10;
    const int hh = (n >> 6) & 15;
    const int dh = n & 63;
    if (region == 2) {
      const size_t baseT = ((size_t)(hb + hh) * 64 + dh) * 2048;
#pragma unroll
      for (int i = 0; i < 4; ++i) {
        const int srow = s0 + wm + i * 16 + quad * 4;
#pragma unroll
        for (int r = 0; r < 4; ++r)
          v[baseT + srow + r] = f2b(acc[i][j][r] + bias);
      }
    } else {
      u16* outp = (region == 0) ? q : kk;
      const float mult = (region == 0) ? QS : 1.0f;
      const size_t base = ((size_t)(hb + hh) * 2048) * 64 + dh;
#pragma unroll
      for (int i = 0; i < 4; ++i) {
        const int srow = s0 + wm + i * 16 + quad * 4;
#pragma unroll
        for (int r = 0; r < 4; ++r)
          outp[base + (size_t)(srow + r) * 64] = f2b((acc[i][j][r] + bias) * mult);
      }
    }
  }
}

// ---------------- K2: flash attention (R15 final form) ----------------
// R22 = revert to R15 (session best, 305.8us total / 130.5us k_attn).
// Occupancy program closed: R18 (reg-cap 32 -> spill), R19 (no dbuf ->
// serial stall), R20 (cap 5 -> spill), R21 (64-row tiles -> 2x staging
// overhead, occupancy unmoved). Constraint triangle {~120-reg footprint,
// dbuf required, 40KB LDS} pins this algorithm at 4 blocks/CU. At R15's
// operating point MFMA(39.8%) + VALU(53%) = ~93% of SIMD issue -> issue-
// saturated; work-removal rounds (R12-R15) only trimmed slack. Next level
// would need fewer instructions/FLOP (32x32-MFMA restructure) - out of
// scope. Techniques stack: MFMA row-sum (R15), defer-max + LDS mask bias
// (R12), in-register P via 16x16x16 PV + pk2 (R11), XCD swizzle (R9),
// K/V double-buffer + 1 barrier/iter (R10), setprio (T5).
__global__ __launch_bounds__(256, 4) void k_attn(
    const u16* __restrict__ q, const u16* __restrict__ k,
    const u16* __restrict__ v, const int* __restrict__ mask,
    u16* __restrict__ attn, int b_fixed) {
  __shared__ __align__(16) float Msmf[2048];     // 8KB mask bias row
  __shared__ __align__(16) u16 Ksm[2][64 * 64];  // 16KB double-buffered
  __shared__ __align__(16) u16 Vsm[2][64 * 64];  // 16KB double-buffered
  const int bid = blockIdx.x;
  const int tid = threadIdx.x, wave = tid >> 6, lane = tid & 63;
  const int col = lane & 15, quad = lane >> 4;
  int qblk, h, b, hb;
  if (b_fixed < 0) {
    // work id w: group w>>4 = (b,h); all 16 q-blocks of a group on one XCD
    const int w = ((bid & 7) << 7) | (bid >> 3);
    qblk = w & 15; h = (w >> 4) & 15; b = w >> 8; hb = b * 16 + h;
  } else {
    qblk = bid & 15; h = bid >> 4; b = b_fixed; hb = h;
  }
  const size_t bh = (size_t)hb * 2048 * 64;

  {  // stage mask row b (2048 int32) into Msmf, convert in place to bias
    const int c = wave * 2;
    gld16(mask + b * 2048 + c * 256 + lane * 4, (char*)Msmf + c * 1024);
    gld16(mask + b * 2048 + (c + 1) * 256 + lane * 4, (char*)Msmf + (c + 1) * 1024);
  }
  __builtin_amdgcn_s_waitcnt(0);
  __syncthreads();
  for (int i = tid; i < 2048; i += 256) {
    const int mi = ((const int*)Msmf)[i];
    Msmf[i] = mi ? -1e30f : 0.f;
  }

  bf16x8 qf[2][2];
#pragma unroll
  for (int qt = 0; qt < 2; ++qt)
#pragma unroll
    for (int c = 0; c < 2; ++c)
      qf[qt][c] = *(const bf16x8*)(q + bh +
                   (size_t)(qblk * 128 + wave * 32 + qt * 16 + col) * 64 + c * 32 + quad * 8);

  const int r8 = lane >> 3, chn = lane & 7;
  const int g = chn ^ r8;
  const int swz = col & 7;

  // cooperative stage of one 64-key K/V tile into buffer `buf`
  auto STAGE = [&](int buf, int kt) {
#pragma unroll
    for (int s = 0; s < 2; ++s) {
      const int row = (wave * 2 + s) * 8 + r8;
      gld16(k + bh + (size_t)(kt * 64 + row) * 64 + g * 8,
            (char*)Ksm[buf] + (wave * 2 + s) * 1024);
      gld16(v + bh + (size_t)row * 2048 + kt * 64 + g * 8,
            (char*)Vsm[buf] + (wave * 2 + s) * 1024);
    }
  };

  f32x4 o[2][4];
#pragma unroll
  for (int qt = 0; qt < 2; ++qt)
#pragma unroll
    for (int n = 0; n < 4; ++n) o[qt][n] = f32x4{0.f, 0.f, 0.f, 0.f};
  f32x4 lacc[2] = {f32x4{0.f, 0.f, 0.f, 0.f}, f32x4{0.f, 0.f, 0.f, 0.f}};
  float mrun[2] = {-1e30f, -1e30f};
  const bf16x4s vones = {0x3F80, 0x3F80, 0x3F80, 0x3F80};  // bf16 1.0 x4

  // prologue: stage kt=0 into buffer 0 (barrier also covers Msmf convert)
  STAGE(0, 0);
  asm volatile("s_waitcnt vmcnt(0)" ::: "memory");
  __syncthreads();

  int cur = 0;
  for (int kt = 0; kt < 32; ++kt) {
    if (kt < 31) STAGE(cur ^ 1, kt + 1);

    // ---- QK: mt-outer, mask bias (from LDS, broadcast) as C-init ----
    f32x4 sc[2][4];  // [qt][mt]
    __builtin_amdgcn_s_setprio(1);
#pragma unroll
    for (int mt = 0; mt < 4; ++mt) {
      const bf16x8 ka0 = *(const bf16x8*)((const char*)Ksm[cur] +
          (mt * 16 + col) * 128 + (quad ^ swz) * 16);
      const bf16x8 ka1 = *(const bf16x8*)((const char*)Ksm[cur] +
          (mt * 16 + col) * 128 + ((4 + quad) ^ swz) * 16);
      const float4 mbv = *(const float4*)(Msmf + kt * 64 + mt * 16 + quad * 4);
#pragma unroll
      for (int qt = 0; qt < 2; ++qt) {
        f32x4 z = {mbv.x, mbv.y, mbv.z, mbv.w};
        z = __builtin_amdgcn_mfma_f32_16x16x32_bf16(ka0, qf[qt][0], z, 0, 0, 0);
        sc[qt][mt] = __builtin_amdgcn_mfma_f32_16x16x32_bf16(ka1, qf[qt][1], z, 0, 0, 0);
      }
    }
    __builtin_amdgcn_s_setprio(0);

    // ---- online softmax with defer-max; P packed in-register via pk2 ----
    float alpha[2];
    int resc[2];
    bf16x4s pa[2][4];  // [qt][mt]: P[q=col][key=quad*4+j] -- matches sc layout
#pragma unroll
    for (int qt = 0; qt < 2; ++qt) {
      float tm = fmaxf(fmaxf(sc[qt][0][0], sc[qt][0][1]),
                       fmaxf(sc[qt][0][2], sc[qt][0][3]));
#pragma unroll
      for (int mt = 1; mt < 4; ++mt)
#pragma unroll
        for (int r = 0; r < 4; ++r) tm = fmaxf(tm, sc[qt][mt][r]);
      tm = fmaxf(tm, __shfl_xor(tm, 16, 64));
      tm = fmaxf(tm, __shfl_xor(tm, 32, 64));
      resc[qt] = __any(tm > mrun[qt]);
      if (resc[qt]) {  // wave-uniform branch
        const float mnew = fmaxf(mrun[qt], tm);
        alpha[qt] = __builtin_amdgcn_exp2f(mrun[qt] - mnew);
        mrun[qt] = mnew;
      } else {
        alpha[qt] = 1.0f;  // exact: mnew == mrun
      }
#pragma unroll
      for (int mt = 0; mt < 4; ++mt) {
#pragma unroll
        for (int r = 0; r < 4; ++r)
          sc[qt][mt][r] = __builtin_amdgcn_exp2f(sc[qt][mt][r] - mrun[qt]);
        uint2 w;
        w.x = pk2(sc[qt][mt][0], sc[qt][mt][1]);
        w.y = pk2(sc[qt][mt][2], sc[qt][mt][3]);
        pa[qt][mt] = __builtin_bit_cast(bf16x4s, w);
      }
    }

    // ---- conditional o/l-rescale (skipped in most iterations) ----
    if (resc[0] | resc[1]) {
      float ar[2][4];
#pragma unroll
      for (int qt = 0; qt < 2; ++qt)
#pragma unroll
        for (int r = 0; r < 4; ++r) ar[qt][r] = __shfl(alpha[qt], quad * 4 + r, 64);
#pragma unroll
      for (int qt = 0; qt < 2; ++qt) {
#pragma unroll
        for (int nt = 0; nt < 4; ++nt)
#pragma unroll
          for (int r = 0; r < 4; ++r) o[qt][nt][r] *= ar[qt][r];
#pragma unroll
        for (int r = 0; r < 4; ++r) lacc[qt][r] *= ar[qt][r];
      }
    }

    // ---- PV: K=16 MFMAs, V fragments as ds_read_b64 (keys quad*4..+3) ----
    __builtin_amdgcn_s_setprio(1);
#pragma unroll
    for (int nt = 0; nt < 4; ++nt) {
      bf16x4s vb[4];
#pragma unroll
      for (int mt = 0; mt < 4; ++mt) {
        // Vsm row = dh = nt*16+col; stored 16B-chunk p holds keys (p^swz)*8
        const uint2 raw = *(const uint2*)((const char*)Vsm[cur] +
            (nt * 16 + col) * 128 + (((mt * 2 + (quad >> 1)) ^ swz) << 4) +
            ((quad & 1) << 3));
        vb[mt] = __builtin_bit_cast(bf16x4s, raw);
      }
#pragma unroll
      for (int qt = 0; qt < 2; ++qt) {
        f32x4 t = o[qt][nt];
#pragma unroll
        for (int mt = 0; mt < 4; ++mt) t = mfma16(pa[qt][mt], vb[mt], t);
        o[qt][nt] = t;
      }
    }
    // row-sum via MFMA: lacc[qt] += P . ones  (B=ones => layout-independent;
    // D-row mapping row=quad*4+r is the same one o's epilogue already uses)
#pragma unroll
    for (int qt = 0; qt < 2; ++qt)
#pragma unroll
      for (int mt = 0; mt < 4; ++mt)
        lacc[qt] = mfma16(pa[qt][mt], vones, lacc[qt]);
    __builtin_amdgcn_s_setprio(0);

    // next-tile loads were issued ~one full compute phase ago
    asm volatile("s_waitcnt vmcnt(0)" ::: "memory");
    __syncthreads();
    cur ^= 1;
  }

  const int arow0 = (b_fixed < 0) ? b * 2048 : 0;
#pragma unroll
  for (int qt = 0; qt < 2; ++qt) {
    float inv[4];
#pragma unroll
    for (int r = 0; r < 4; ++r) inv[r] = 1.0f / lacc[qt][r];
#pragma unroll
    for (int n = 0; n < 4; ++n)
#pragma unroll
      for (int r = 0; r < 4; ++r) {
        const int srow = qblk * 128 + wave * 32 + qt * 16 + quad * 4 + r;
        const size_t idx = ((size_t)(arow0 + srow)) * 1024 + h * 64 + n * 16 + col;
        attn[idx] = f2b(o[qt][n][r] * inv[r]);
      }
  }
}

// ---------------- K3a: output projection, all-bf16 staging ----------------
__global__ __launch_bounds__(256, 2) void k_proj_a(
    const u16* __restrict__ attn, const u16* __restrict__ wb,
    const float* __restrict__ bproj, float* __restrict__ out) {
  __shared__ __align__(16) u16 Asm[128 * 32];
  __shared__ __align__(16) u16 Bsm[128 * 32];
  const int bn = blockIdx.x;  // 0..7
  const int bm = blockIdx.y;  // 0..63
  const int tid = threadIdx.x;
  const int wave = tid >> 6, lane = tid & 63;
  const int col = lane & 15, quad = lane >> 4;
  const int b = bm >> 4;
  const int s0 = (bm & 15) * 128;
  const int c0 = wave * 2;
  const int srow0 = c0 * 16 + (lane >> 2);
  const int kc = (lane & 3) * 8;
  const u16* gA0 = attn + (size_t)(bm * 128 + srow0) * 1024 + kc;
  const u16* gA1 = attn + (size_t)(bm * 128 + srow0 + 16) * 1024 + kc;
  const u16* gB0 = wb + (size_t)(bn * 128 + srow0) * 1024 + kc;
  const u16* gB1 = wb + (size_t)(bn * 128 + srow0 + 16) * 1024 + kc;
  u16* lA0 = Asm + c0 * 512;
  u16* lA1 = Asm + c0 * 512 + 512;
  u16* lB0 = Bsm + c0 * 512;
  u16* lB1 = Bsm + c0 * 512 + 512;
  const int wm = (wave >> 1) * 64, wn = (wave & 1) * 64;

  f32x4 acc[4][4];
#pragma unroll
  for (int i = 0; i < 4; ++i)
#pragma unroll
    for (int j = 0; j < 4; ++j) acc[i][j] = f32x4{0.f, 0.f, 0.f, 0.f};

  for (int k0 = 0; k0 < 1024; k0 += 32) {
    __syncthreads();
    gld16(gA0 + k0, lA0);
    gld16(gA1 + k0, lA1);
    gld16(gB0 + k0, lB0);
    gld16(gB1 + k0, lB1);
    __builtin_amdgcn_s_waitcnt(0);
    __syncthreads();
    bf16x8 af[4], bfr[4];
#pragma unroll
    for (int i = 0; i < 4; ++i)
      af[i] = *(const bf16x8*)(Asm + (wm + i * 16 + col) * 32 + quad * 8);
#pragma unroll
    for (int j = 0; j < 4; ++j)
      bfr[j] = *(const bf16x8*)(Bsm + (wn + j * 16 + col) * 32 + quad * 8);
#pragma unroll
    for (int i = 0; i < 4; ++i)
#pragma unroll
      for (int j = 0; j < 4; ++j)
        acc[i][j] = __builtin_amdgcn_mfma_f32_16x16x32_bf16(af[i], bfr[j], acc[i][j], 0, 0, 0);
  }

#pragma unroll
  for (int j = 0; j < 4; ++j) {
    const int n = bn * 128 + wn + j * 16 + col;
    const float bias = bproj[n];
#pragma unroll
    for (int i = 0; i < 4; ++i) {
      const int srow = s0 + wm + i * 16 + quad * 4;
#pragma unroll
      for (int r = 0; r < 4; ++r)
        out[(size_t)((srow + r) * 4 + b) * 1024 + n] = acc[i][j][r] + bias;
    }
  }
}

// ---------------- K3b: output projection, inline-convert B (fallback) ----------------
__global__ __launch_bounds__(256, 2) void k_proj_f32(
    const u16* __restrict__ attn, const float* __restrict__ Wproj,
    const float* __restrict__ bproj, float* __restrict__ out, int b_fixed) {
  __shared__ __align__(16) u16 Asm[128 * 32];
  __shared__ __align__(16) u16 Bsm[128 * 32];
  const int bn = blockIdx.x;
  const int bm = blockIdx.y;
  const int tid = threadIdx.x;
  const int wave = tid >> 6, lane = tid & 63;
  const int col = lane & 15, quad = lane >> 4;
  int b, s0;
  if (b_fixed < 0) { b = bm >> 4; s0 = (bm & 15) * 128; }
  else             { b = b_fixed; s0 = bm * 128; }

  const int c0 = wave * 2;
  const int srow0 = c0 * 16 + (lane >> 2);
  const int kc = (lane & 3) * 8;
  const u16* gA0 = attn + (size_t)(bm * 128 + srow0) * 1024 + kc;
  const u16* gA1 = attn + (size_t)(bm * 128 + srow0 + 16) * 1024 + kc;
  u16* lA0 = Asm + c0 * 512;
  u16* lA1 = Asm + c0 * 512 + 512;
  const int brow = tid >> 1;
  const int kseg = (tid & 1) * 16;
  const float* gB = Wproj + (size_t)(bn * 128 + brow) * 1024 + kseg;
  u16* lB = Bsm + brow * 32 + kseg;
  const int wm = (wave >> 1) * 64, wn = (wave & 1) * 64;

  f32x4 acc[4][4];
#pragma unroll
  for (int i = 0; i < 4; ++i)
#pragma unroll
    for (int j = 0; j < 4; ++j) acc[i][j] = f32x4{0.f, 0.f, 0.f, 0.f};

  for (int k0 = 0; k0 < 1024; k0 += 32) {
    float4 bv[4];
#pragma unroll
    for (int u = 0; u < 4; ++u) bv[u] = *(const float4*)(gB + k0 + u * 4);
    __syncthreads();
    gld16(gA0 + k0, lA0);
    gld16(gA1 + k0, lA1);
    cvt16_store(bv, lB);
    __builtin_amdgcn_s_waitcnt(0);
    __syncthreads();
    bf16x8 af[4], bfr[4];
#pragma unroll
    for (int i = 0; i < 4; ++i)
      af[i] = *(const bf16x8*)(Asm + (wm + i * 16 + col) * 32 + quad * 8);
#pragma unroll
    for (int j = 0; j < 4; ++j)
      bfr[j] = *(const bf16x8*)(Bsm + (wn + j * 16 + col) * 32 + quad * 8);
#pragma unroll
    for (int i = 0; i < 4; ++i)
#pragma unroll
      for (int j = 0; j < 4; ++j)
        acc[i][j] = __builtin_amdgcn_mfma_f32_16x16x32_bf16(af[i], bfr[j], acc[i][j], 0, 0, 0);
  }

#pragma unroll
  for (int j = 0; j < 4; ++j) {
    const int n = bn * 128 + wn + j * 16 + col;
    const float bias = bproj[n];
#pragma unroll
    for (int i = 0; i < 4; ++i) {
      const int srow = s0 + wm + i * 16 + quad * 4;
#pragma unroll
      for (int r = 0; r < 4; ++r)
        out[(size_t)((srow + r) * 4 + b) * 1024 + n] = acc[i][j][r] + bias;
    }
  }
}

extern "C" void kernel_launch(void* const* d_in, const int* in_sizes, int n_in,
                              void* d_out, int out_size, void* d_ws, size_t ws_size,
                              hipStream_t stream) {
  const float* inp = (const float*)d_in[0];
  const int* mask = (const int*)d_in[1];
  const float* Wqkv = (const float*)d_in[2];
  const float* bqkv = (const float*)d_in[3];
  const float* Wproj = (const float*)d_in[4];
  const float* bproj = (const float*)d_in[5];
  float* out = (float*)d_out;

  const size_t FULLSZ = (size_t)BATCH * NHEAD * SEQ * DHEAD;  // 8388608 elems
  const size_t WQKV_E = (size_t)3 * DIM * DIM;                // 3145728
  const size_t WPROJ_E = (size_t)DIM * DIM;                   // 1048576
  const size_t pathA_bytes = (4 * FULLSZ + WQKV_E + WPROJ_E) * sizeof(u16);  // 75.5 MB

  if (ws_size >= pathA_bytes) {
    // Path A: convert-once + all-async-bf16 GEMMs.
    u16* q = (u16*)d_ws;
    u16* kk = q + FULLSZ;
    u16* v = kk + FULLSZ;
    u16* xb = v + FULLSZ;      // converted inp; later overwritten as attn buffer
    u16* attn = xb;            // alias — k_attn writes after k_qkv_a finished reading
    u16* wqkvb = xb + FULLSZ;
    u16* wprojb = wqkvb + WQKV_E;
    k_cvt<<<dim3(12288), 256, 0, stream>>>(inp, Wqkv, Wproj, xb, wqkvb, wprojb);
    k_qkv_a<<<dim3(24, 64), 256, 0, stream>>>(xb, wqkvb, bqkv, q, kk, v);
    k_attn<<<dim3(1024), 256, 0, stream>>>(q, kk, v, mask, attn, -1);
    k_proj_a<<<dim3(8, 64), 256, 0, stream>>>(attn, wprojb, bproj, out);
  } else if (ws_size >= 4 * FULLSZ * sizeof(u16)) {
    // Path B: proven R5 pipeline (inline f32 convert).
    u16* q = (u16*)d_ws;
    u16* kk = q + FULLSZ;
    u16* v = kk + FULLSZ;
    u16* attn = v + FULLSZ;
    k_qkv_f32<<<dim3(24, 64), 256, 0, stream>>>(inp, Wqkv, bqkv, q, kk, v, -1);
    k_attn<<<dim3(1024), 256, 0, stream>>>(q, kk, v, mask, attn, -1);
    k_proj_f32<<<dim3(8, 64), 256, 0, stream>>>(attn, Wproj, bproj, out, -1);
  } else {
    // Path C: per-batch pipeline, 16 MiB workspace.
    const size_t BSZ = (size_t)NHEAD * SEQ * DHEAD;
    u16* q = (u16*)d_ws;
    u16* kk = q + BSZ;
    u16* v = kk + BSZ;
    u16* attn = v + BSZ;
    for (int b = 0; b < BATCH; ++b) {
      k_qkv_f32<<<dim3(24, 16), 256, 0, stream>>>(inp, Wqkv, bqkv, q, kk, v, b);
      k_attn<<<dim3(256), 256, 0, stream>>>(q, kk, v, mask, attn, b);
      k_proj_f32<<<dim3(8, 16), 256, 0, stream>>>(attn, Wproj, bproj, out, b);
    }
  }
}